// Round 1
// baseline (6127.556 us; speedup 1.0000x reference)
//
#include <hip/hip_runtime.h>

// ---------------------------------------------------------------------------
// Bidirectional GRU encoder (Keras v2 semantics, reset_after=True, mask_zero)
//   tokens[128,256] -> emb[32000,512] -> xp = x@Wx+b0 (both dirs)
//   scan: rec = h@Wh + b1; z=sig(xz+rz); r=sig(xr+rr); hh=tanh(xh+r*rh)
//         h = mask ? z*h+(1-z)*hh : h
//   out[B,T,2U] = concat(out_f, out_b);  hidden = [h_f|h_b]@fc_W + fc_b
// Strategy: bf16 MFMA (16x16x32) for all matmuls, f32 master state.
// ---------------------------------------------------------------------------

#define T_SEQ 256
#define BATCH 128
#define EMB_D 512
#define UNITS 1024
#define NROWS (BATCH * T_SEQ) /* 32768 */
#define N3U 3072
#define N6U 6144

typedef __attribute__((ext_vector_type(8))) __bf16 bfv8;
typedef __attribute__((ext_vector_type(4))) float f32x4;

__device__ inline unsigned short f2bf(float f) {
  union { float f; unsigned int u; } x; x.f = f;
  unsigned int u = x.u;
  unsigned int r = (u + 0x7fffu + ((u >> 16) & 1u)) >> 16; // RNE
  return (unsigned short)r;
}
__device__ inline float bf2f(unsigned short h) {
  union { unsigned int u; float f; } x; x.u = ((unsigned int)h) << 16;
  return x.f;
}
__device__ inline f32x4 mfma16(bfv8 a, bfv8 b, f32x4 c) {
  return __builtin_amdgcn_mfma_f32_16x16x32_bf16(a, b, c, 0, 0, 0);
}

// dst[N][K] (bf16) = src[K][N] (f32), 32x32 LDS-tiled transpose
__global__ __launch_bounds__(256) void k_transpose(const float* __restrict__ src,
                                                   unsigned short* __restrict__ dst,
                                                   int K, int N) {
  __shared__ float tile[32][33];
  int k0 = blockIdx.x * 32, n0 = blockIdx.y * 32;
  int tx = threadIdx.x & 31, ty = threadIdx.x >> 5;
#pragma unroll
  for (int i = 0; i < 4; ++i)
    tile[ty + i * 8][tx] = src[(size_t)(k0 + ty + i * 8) * N + n0 + tx];
  __syncthreads();
#pragma unroll
  for (int i = 0; i < 4; ++i)
    dst[(size_t)(n0 + ty + i * 8) * K + k0 + tx] = f2bf(tile[tx][ty + i * 8]);
}

// Xbf[32768][512] bf16 = emb[tokens[row]]
__global__ __launch_bounds__(256) void k_gather(const int* __restrict__ tokens,
                                                const float* __restrict__ emb,
                                                unsigned short* __restrict__ Xbf) {
  int idx = blockIdx.x * 256 + threadIdx.x; // one float4 per thread
  int row = idx >> 7;
  int c4 = (idx & 127) * 4;
  int tok = tokens[row];
  float4 v = *(const float4*)(emb + (size_t)tok * EMB_D + c4);
  ushort4 p;
  p.x = f2bf(v.x); p.y = f2bf(v.y); p.z = f2bf(v.z); p.w = f2bf(v.w);
  *(ushort4*)(Xbf + (size_t)row * EMB_D + c4) = p;
}

// biasX[6144] = [b_f[0] | b_b[0]],  biasH[6144] = [b_f[1] | b_b[1]]
__global__ __launch_bounds__(256) void k_bias(const float* __restrict__ bf_,
                                              const float* __restrict__ bb_,
                                              float* __restrict__ biasX,
                                              float* __restrict__ biasH) {
  int i = blockIdx.x * 256 + threadIdx.x;
  if (i >= N6U) return;
  if (i < N3U) { biasX[i] = bf_[i];        biasH[i] = bf_[N3U + i]; }
  else         { biasX[i] = bb_[i - N3U];  biasH[i] = bb_[i]; }
}

// C[M][N] = A[M][K](bf16) @ BT[N][K](bf16)^T + bias[N]
// 128x128 tile, 4 waves (each 64x64 = 4x4 MFMA frags), BK=32, reg-staged LDS.
__global__ __launch_bounds__(256) void k_gemm(const unsigned short* __restrict__ A,
                                              const unsigned short* __restrict__ BT,
                                              const float* __restrict__ bias,
                                              void* __restrict__ C,
                                              int M, int N, int K, int out_f32) {
  __shared__ unsigned short As[128 * 32];
  __shared__ unsigned short Bs[128 * 32];
  const int mt = blockIdx.x, nt = blockIdx.y;
  const int tid = threadIdx.x;
  const int wid = tid >> 6, lane = tid & 63;
  const int wm = (wid >> 1) * 64, wn = (wid & 1) * 64;
  const int l15 = lane & 15, lk = (lane >> 4) * 8;

  f32x4 acc[4][4];
#pragma unroll
  for (int i = 0; i < 4; ++i)
#pragma unroll
    for (int j = 0; j < 4; ++j) acc[i][j] = (f32x4){0.f, 0.f, 0.f, 0.f};

  const int r = tid >> 2;          // staging row 0..63
  const int cc = (tid & 3) * 8;    // staging col (elements)
  const unsigned short* ga0 = A + (size_t)(mt * 128 + r) * K + cc;
  const unsigned short* ga1 = ga0 + (size_t)64 * K;
  const unsigned short* gb0 = BT + (size_t)(nt * 128 + r) * K + cc;
  const unsigned short* gb1 = gb0 + (size_t)64 * K;

  for (int k0 = 0; k0 < K; k0 += 32) {
    uint4 va0 = *(const uint4*)(ga0 + k0);
    uint4 va1 = *(const uint4*)(ga1 + k0);
    uint4 vb0 = *(const uint4*)(gb0 + k0);
    uint4 vb1 = *(const uint4*)(gb1 + k0);
    __syncthreads(); // previous iter's LDS reads complete
    *(uint4*)(As + r * 32 + cc) = va0;
    *(uint4*)(As + (64 + r) * 32 + cc) = va1;
    *(uint4*)(Bs + r * 32 + cc) = vb0;
    *(uint4*)(Bs + (64 + r) * 32 + cc) = vb1;
    __syncthreads();
    bfv8 af[4], bfr[4];
#pragma unroll
    for (int i = 0; i < 4; ++i) {
      af[i]  = *(const bfv8*)(As + (wm + i * 16 + l15) * 32 + lk);
      bfr[i] = *(const bfv8*)(Bs + (wn + i * 16 + l15) * 32 + lk);
    }
#pragma unroll
    for (int i = 0; i < 4; ++i)
#pragma unroll
      for (int j = 0; j < 4; ++j) acc[i][j] = mfma16(af[i], bfr[j], acc[i][j]);
  }

#pragma unroll
  for (int j = 0; j < 4; ++j) {
    int col = nt * 128 + wn + j * 16 + l15;
    float bv = bias[col];
#pragma unroll
    for (int i = 0; i < 4; ++i) {
      int row0 = mt * 128 + wm + i * 16 + (lane >> 4) * 4;
#pragma unroll
      for (int q = 0; q < 4; ++q) {
        float v = acc[i][j][q] + bv;
        if (out_f32) ((float*)C)[(size_t)(row0 + q) * N + col] = v;
        else ((unsigned short*)C)[(size_t)(row0 + q) * N + col] = f2bf(v);
      }
    }
  }
}

// One GRU time step, both directions. Grid: (64 u-tiles, 2 m-groups, 2 dirs),
// 4 waves each computing 16(batch) x 16(U) with 3 gate accumulators, K=1024.
// Operands straight from global (L2-hot: h bf16 = 512KB, WhT slices reused).
__global__ __launch_bounds__(256) void k_step(const unsigned short* __restrict__ XP,
                                              const unsigned short* __restrict__ WhT,
                                              const float* __restrict__ biasH,
                                              const int* __restrict__ tokens,
                                              float* __restrict__ hmas,
                                              unsigned short* __restrict__ hbf,
                                              float* __restrict__ out,
                                              int step) {
  const int dir = blockIdx.z;
  const int t = dir ? (T_SEQ - 1 - step) : step;
  const int u0 = blockIdx.x * 16;
  const int m0 = blockIdx.y * 64;
  const int wid = threadIdx.x >> 6, lane = threadIdx.x & 63;
  const int l15 = lane & 15, lk = (lane >> 4) * 8;

  const unsigned short* ap = hbf + (size_t)(m0 + wid * 16 + l15) * 2048 + dir * 1024 + lk;
  const unsigned short* bp = WhT + (size_t)(dir * N3U + u0 + l15) * 1024 + lk;
  const size_t G = (size_t)1024 * 1024; // gate stride in WhT (1024 rows)

  f32x4 az0 = {0.f,0.f,0.f,0.f}, az1 = az0, ar0 = az0, ar1 = az0, ah0 = az0, ah1 = az0;
#pragma unroll 4
  for (int k = 0; k < 1024; k += 64) {
    bfv8 a0 = *(const bfv8*)(ap + k);
    bfv8 a1 = *(const bfv8*)(ap + k + 32);
    bfv8 bz0 = *(const bfv8*)(bp + k);
    bfv8 bz1 = *(const bfv8*)(bp + k + 32);
    bfv8 br0 = *(const bfv8*)(bp + G + k);
    bfv8 br1 = *(const bfv8*)(bp + G + k + 32);
    bfv8 bh0 = *(const bfv8*)(bp + 2 * G + k);
    bfv8 bh1 = *(const bfv8*)(bp + 2 * G + k + 32);
    az0 = mfma16(a0, bz0, az0); az1 = mfma16(a1, bz1, az1);
    ar0 = mfma16(a0, br0, ar0); ar1 = mfma16(a1, br1, ar1);
    ah0 = mfma16(a0, bh0, ah0); ah1 = mfma16(a1, bh1, ah1);
  }
  f32x4 az = az0 + az1, ar = ar0 + ar1, ah = ah0 + ah1;

  const int u = u0 + l15;
  const float bz = biasH[dir * N3U + u];
  const float br = biasH[dir * N3U + 1024 + u];
  const float bh = biasH[dir * N3U + 2048 + u];
#pragma unroll
  for (int q = 0; q < 4; ++q) {
    int b = m0 + wid * 16 + (lane >> 4) * 4 + q;
    size_t xpo = ((size_t)(b * T_SEQ + t)) * N6U + dir * N3U + u;
    float xz = bf2f(XP[xpo]);
    float xr = bf2f(XP[xpo + 1024]);
    float xh = bf2f(XP[xpo + 2048]);
    float rz = az[q] + bz, rr = ar[q] + br, rh = ah[q] + bh;
    float z = 1.f / (1.f + __expf(-(xz + rz)));
    float rg = 1.f / (1.f + __expf(-(xr + rr)));
    float hh = tanhf(xh + rg * rh);
    size_t hoff = (size_t)(dir * BATCH + b) * 1024 + u;
    float hp = hmas[hoff];
    float hn = z * hp + (1.f - z) * hh;
    if (tokens[b * T_SEQ + t] == 0) hn = hp; // masked step carries state
    hmas[hoff] = hn;
    hbf[(size_t)b * 2048 + dir * 1024 + u] = f2bf(hn);
    out[((size_t)b * T_SEQ + t) * 2048 + dir * 1024 + u] = hn;
  }
}

extern "C" void kernel_launch(void* const* d_in, const int* in_sizes, int n_in,
                              void* d_out, int out_size, void* d_ws, size_t ws_size,
                              hipStream_t stream) {
  const int* tokens = (const int*)d_in[0];
  const float* emb  = (const float*)d_in[1];
  const float* Wx_f = (const float*)d_in[2];
  const float* Wh_f = (const float*)d_in[3];
  const float* b_f  = (const float*)d_in[4];
  const float* Wx_b = (const float*)d_in[5];
  const float* Wh_b = (const float*)d_in[6];
  const float* b_b  = (const float*)d_in[7];
  const float* fc_W = (const float*)d_in[8];
  const float* fc_b = (const float*)d_in[9];
  float* out = (float*)d_out;

  // workspace layout (~440 MB)
  char* w = (char*)d_ws;
  unsigned short* XP  = (unsigned short*)w; w += (size_t)NROWS * N6U * 2;   // 384 MiB
  unsigned short* Xbf = (unsigned short*)w; w += (size_t)NROWS * EMB_D * 2; // 32 MiB
  unsigned short* WxT = (unsigned short*)w; w += (size_t)N6U * EMB_D * 2;   // 6 MiB
  unsigned short* WhT = (unsigned short*)w; w += (size_t)N6U * UNITS * 2;   // 12 MiB
  unsigned short* fcWT = (unsigned short*)w; w += (size_t)UNITS * 2048 * 2; // 4 MiB
  float* hmas = (float*)w; w += (size_t)2 * BATCH * UNITS * 4;              // 1 MiB
  unsigned short* hbf = (unsigned short*)w; w += (size_t)BATCH * 2048 * 2;  // 0.5 MiB
  float* biasX = (float*)w; w += N6U * 4;
  float* biasH = (float*)w; w += N6U * 4;

  hipMemsetAsync(hmas, 0, (size_t)2 * BATCH * UNITS * 4, stream);
  hipMemsetAsync((void*)hbf, 0, (size_t)BATCH * 2048 * 2, stream);

  // weight transposes (f32 -> bf16, [N][K] layouts)
  k_transpose<<<dim3(EMB_D / 32, N3U / 32), 256, 0, stream>>>(Wx_f, WxT, EMB_D, N3U);
  k_transpose<<<dim3(EMB_D / 32, N3U / 32), 256, 0, stream>>>(Wx_b, WxT + (size_t)N3U * EMB_D, EMB_D, N3U);
  k_transpose<<<dim3(UNITS / 32, N3U / 32), 256, 0, stream>>>(Wh_f, WhT, UNITS, N3U);
  k_transpose<<<dim3(UNITS / 32, N3U / 32), 256, 0, stream>>>(Wh_b, WhT + (size_t)N3U * UNITS, UNITS, N3U);
  k_transpose<<<dim3(2048 / 32, 1024 / 32), 256, 0, stream>>>(fc_W, fcWT, 2048, 1024);
  k_bias<<<24, 256, 0, stream>>>(b_f, b_b, biasX, biasH);
  k_gather<<<(NROWS * 128) / 256, 256, 0, stream>>>(tokens, emb, Xbf);

  // input projections for both directions: XP[32768][6144] bf16
  k_gemm<<<dim3(NROWS / 128, N6U / 128), 256, 0, stream>>>(Xbf, WxT, biasX, XP, NROWS, N6U, EMB_D, 0);

  // sequential scan, fwd + bwd concurrently
  for (int s = 0; s < T_SEQ; ++s)
    k_step<<<dim3(64, 2, 2), 256, 0, stream>>>(XP, WhT, biasH, tokens, hmas, hbf, out, s);

  // hidden = [h_f|h_b] @ fc_W + fc_b  (f32 out)
  k_gemm<<<dim3(1, 8), 256, 0, stream>>>(hbf, fcWT, fc_b, out + (size_t)NROWS * 2048, BATCH, UNITS, 2048, 1);
}